// Round 16
// baseline (60.363 us; speedup 1.0000x reference)
//
#include <hip/hip_runtime.h>

#define BB 2048
#define UU 4096
#define CH 512
#define NCH (UU / CH)   // 8 chunks per row

#if __has_builtin(__builtin_amdgcn_fractf)
#define FRACTF(x) __builtin_amdgcn_fractf(x)
#else
#define FRACTF(x) ((x) - floorf(x))
#endif

#if __has_builtin(__builtin_amdgcn_fmed3f)
#define FMED3(a,b,c) __builtin_amdgcn_fmed3f((a),(b),(c))
#else
__device__ __forceinline__ float FMED3(float a, float b, float c) {
    return fmaxf(fminf(a, b), fminf(fmaxf(a, b), c));
}
#endif

// One row per 64-thread block. Lane l owns columns [base + 8l, base + 8l + 8).
// Serial carry crosses lanes via readlane broadcast; step is
// c' = med3(fract(s), s + A, A), s = d' + c, A = -m'  (bit-exact vs reference;
// inactive elements substituted d'=1, A=-1 make the step an exact identity on
// c in [-1,1)). frames reconstructed wave-parallel post-loop from saved c-in.
__global__ __launch_bounds__(64) void row_kernel(
    const float* __restrict__ dur,
    const float* __restrict__ speech,
    const float* __restrict__ residual_prev,
    const float* __restrict__ cached_prev,
    const int* __restrict__ unit_len,
    const int* __restrict__ sealed_len,
    const int* __restrict__ committed_prev,
    float* __restrict__ out)
{
    float* mat   = out;
    float* proj  = out + (size_t)BB * UU;
    float* resid = out + 2 * (size_t)BB * UU;
    float* cach  = resid + BB;
    float* comm  = cach + (size_t)BB * UU;

    const int r = (int)blockIdx.x;
    const int l = (int)threadIdx.x;
    int L = min(unit_len[r], sealed_len[r]); L = max(0, min(L, UU));
    int P = committed_prev[r];               P = max(0, min(P, UU));
    const unsigned span = (L > P) ? (unsigned)(L - P) : 0u;
    float carry = residual_prev[r];
    const size_t ro = (size_t)r * UU;
    const int off = l << 3;

    float4 z4 = make_float4(0.f, 0.f, 0.f, 0.f);
    float4 dA0=z4,dA1=z4,sA0=z4,sA1=z4,cA0=z4,cA1=z4;
    float4 dB0=z4,dB1=z4,sB0=z4,sB1=z4,cB0=z4,cB1=z4;

    // prologue: load chunk 0 (uniform-per-row conditionals)
    {
        const bool needDS = (0 < L) && (CH > P);
        const bool needC  = (P > 0);
        if (needDS) {
            dA0 = *(const float4*)(dur + ro + off);
            dA1 = *(const float4*)(dur + ro + off + 4);
            sA0 = *(const float4*)(speech + ro + off);
            sA1 = *(const float4*)(speech + ro + off + 4);
        }
        if (needC) {
            cA0 = *(const float4*)(cached_prev + ro + off);
            cA1 = *(const float4*)(cached_prev + ro + off + 4);
        }
    }

    #pragma unroll 1
    for (int k = 0; k < NCH; ++k) {
        const int base = k * CH;
        // prefetch next chunk into B regs
        if (k + 1 < NCH) {
            const int nb = base + CH;
            const bool needDS = (nb < L) && (nb + CH > P);
            const bool needC  = (nb < P);
            if (needDS) {
                dB0 = *(const float4*)(dur + ro + nb + off);
                dB1 = *(const float4*)(dur + ro + nb + off + 4);
                sB0 = *(const float4*)(speech + ro + nb + off);
                sB1 = *(const float4*)(speech + ro + nb + off + 4);
            }
            if (needC) {
                cB0 = *(const float4*)(cached_prev + ro + nb + off);
                cB1 = *(const float4*)(cached_prev + ro + nb + off + 4);
            }
        }
        // all but the <=6 newest VM ops retired => chunk k's loads landed
        // (loads(k) are older than this iteration's <=6 prefetch loads and
        //  older than last iteration's stores; safe head/steady/tail).
        asm volatile("s_waitcnt vmcnt(6)" ::: "memory");

        // wave-parallel prep: identity substitution for inactive elements
        float dd[8] = {dA0.x,dA0.y,dA0.z,dA0.w,dA1.x,dA1.y,dA1.z,dA1.w};
        float ss[8] = {sA0.x,sA0.y,sA0.z,sA0.w,sA1.x,sA1.y,sA1.z,sA1.w};
        float cp[8] = {cA0.x,cA0.y,cA0.z,cA0.w,cA1.x,cA1.y,cA1.z,cA1.w};
        const int kb = base + off - P;
        float dp[8], Am[8];
        #pragma unroll
        for (int j = 0; j < 8; ++j) {
            bool va = (unsigned)(kb + j) < span;
            dp[j] = va ? dd[j] : 1.0f;
            Am[j] = (va && (ss[j] <= 0.5f)) ? 0.0f : -1.0f;   // A = -m'
        }

        // serial segment: only lanes intersecting [P, L)
        const int lo = (max(0, P - base)) >> 3;
        const int hi = (min(CH, max(0, L - base)) + 7) >> 3;
        float cin = 0.f;
        for (int i = lo; i < hi; ++i) {
            cin = (l == i) ? carry : cin;          // save lane i's carry-in
            float cc = carry;
            #pragma unroll
            for (int j = 0; j < 8; ++j) {
                float s = dp[j] + cc;
                cc = FMED3(FRACTF(s), s + Am[j], Am[j]);   // 3-dep-level step
            }
            carry = __int_as_float(__builtin_amdgcn_readlane(__float_as_int(cc), i));
        }

        // wave-parallel post: reconstruct frames + final values (off serial path)
        float pj[8], mt[8];
        float c2 = cin;
        #pragma unroll
        for (int j = 0; j < 8; ++j) {
            float s  = dp[j] + c2;
            float t1 = fmaxf(s, 0.f);
            float cc = FMED3(FRACTF(s), s + Am[j], Am[j]);
            float fv = t1 - cc;                    // frames
            c2 = cc;
            int u = base + off + j;
            bool va = (unsigned)(u - P) < span;
            float p_ = va ? fv : ((u < P) ? cp[j] : 0.f);
            pj[j] = p_;
            mt[j] = (u < L) ? p_ : 0.f;
        }
        {
            float* pm = mat  + ro + base + off;
            float* pp = proj + ro + base + off;
            float* pc = cach + ro + base + off;
            *(float4*)(pm)     = make_float4(mt[0], mt[1], mt[2], mt[3]);
            *(float4*)(pm + 4) = make_float4(mt[4], mt[5], mt[6], mt[7]);
            *(float4*)(pp)     = make_float4(pj[0], pj[1], pj[2], pj[3]);
            *(float4*)(pp + 4) = make_float4(pj[4], pj[5], pj[6], pj[7]);
            *(float4*)(pc)     = make_float4(mt[0], mt[1], mt[2], mt[3]);
            *(float4*)(pc + 4) = make_float4(mt[4], mt[5], mt[6], mt[7]);
        }
        // pin store issue before next iteration's prefetch (keeps vmcnt math)
        asm volatile("" ::: "memory");

        dA0=dB0; dA1=dB1; sA0=sB0; sA1=sB1; cA0=cB0; cA1=cB1;
    }

    if (l == 0) {
        resid[r] = carry;
        comm[r]  = (float)L;
    }
}

extern "C" void kernel_launch(void* const* d_in, const int* in_sizes, int n_in,
                              void* d_out, int out_size, void* d_ws, size_t ws_size,
                              hipStream_t stream) {
    const float* dur            = (const float*)d_in[0];
    const float* speech         = (const float*)d_in[1];
    const float* residual_prev  = (const float*)d_in[2];
    const float* cached_prev    = (const float*)d_in[3];
    const int*   unit_len       = (const int*)d_in[4];
    const int*   sealed_len     = (const int*)d_in[5];
    const int*   committed_prev = (const int*)d_in[6];

    row_kernel<<<BB, 64, 0, stream>>>(dur, speech, residual_prev, cached_prev,
                                      unit_len, sealed_len, committed_prev,
                                      (float*)d_out);
}

// Round 17
// 58.511 us; speedup vs baseline: 1.0317x; 1.0317x over previous
//
#include <hip/hip_runtime.h>

#define BB 2048
#define UU 4096
#define CH 512
#define NCH (UU / CH)   // 8 chunks per row

typedef float f32x4 __attribute__((ext_vector_type(4)));

#if __has_builtin(__builtin_amdgcn_fractf)
#define FRACTF(x) __builtin_amdgcn_fractf(x)
#else
#define FRACTF(x) ((x) - floorf(x))
#endif

#if __has_builtin(__builtin_amdgcn_fmed3f)
#define FMED3(a,b,c) __builtin_amdgcn_fmed3f((a),(b),(c))
#else
__device__ __forceinline__ float FMED3(float a, float b, float c) {
    return fmaxf(fminf(a, b), fminf(fmaxf(a, b), c));
}
#endif

// hand-issued VMEM: compiler cannot sink/reorder these (volatile + "memory"),
// and emits no waitcnt for them — waits are OUR counted vmcnt asm only.
#define LD4(r, p) asm volatile("global_load_dwordx4 %0, %1, off" \
                               : "=v"(r) : "v"(p) : "memory")
#define ST4(p, v) asm volatile("global_store_dwordx4 %0, %1, off" \
                               :: "v"(p), "v"(v) : "memory")
#define WAITV(N)  do { asm volatile("s_waitcnt vmcnt(" #N ")" ::: "memory"); \
                       __builtin_amdgcn_sched_barrier(0); } while (0)

// One row per 64-thread block. Lane l owns columns [base+8l, base+8l+8).
// Serial carry crosses lanes via readlane; step c' = med3(fract(s), s+A, A),
// s = d'+c, A = -m' (bit-exact; inactive subst d'=1, A=-1 is identity on
// c in [-1,1)). frames reconstructed wave-parallel from saved carry-in.
__global__ __launch_bounds__(64) void row_kernel(
    const float* __restrict__ dur,
    const float* __restrict__ speech,
    const float* __restrict__ residual_prev,
    const float* __restrict__ cached_prev,
    const int* __restrict__ unit_len,
    const int* __restrict__ sealed_len,
    const int* __restrict__ committed_prev,
    float* __restrict__ out)
{
    float* mat   = out;
    float* proj  = out + (size_t)BB * UU;
    float* resid = out + 2 * (size_t)BB * UU;
    float* cach  = resid + BB;
    float* comm  = cach + (size_t)BB * UU;

    const int r = (int)blockIdx.x;
    const int l = (int)threadIdx.x;
    int L = min(unit_len[r], sealed_len[r]); L = max(0, min(L, UU));
    int P = committed_prev[r];               P = max(0, min(P, 1024));
    const unsigned span = (L > P) ? (unsigned)(L - P) : 0u;
    float carry = residual_prev[r];
    const size_t ro = (size_t)r * UU;
    const int off = l << 3;

    f32x4 dA0, dA1, sA0, sA1, cA0, cA1;
    f32x4 dB0, dB1, sB0, sB1, cB0, cB1;

    // prologue: chunk 0 (6 loads: d,s,cached)
    {
        const float* pd = dur + ro + off;
        const float* ps = speech + ro + off;
        const float* pc = cached_prev + ro + off;
        LD4(dA0, pd); LD4(dA1, pd + 4);
        LD4(sA0, ps); LD4(sA1, ps + 4);
        LD4(cA0, pc); LD4(cA1, pc + 4);
    }

// PRE: issue chunk K+1 loads into set Y (CN: cached too, chunks 0/1 only).
// CC: this chunk's compute uses cached regs.
#define PHASE(K, X, Y, PRE, CN, CC, NWAIT) do {                               \
        const int base_ = (K) * CH;                                           \
        if (PRE) {                                                            \
            const float* pd_ = dur + ro + base_ + CH + off;                   \
            const float* ps_ = speech + ro + base_ + CH + off;                \
            LD4(d##Y##0, pd_); LD4(d##Y##1, pd_ + 4);                         \
            LD4(s##Y##0, ps_); LD4(s##Y##1, ps_ + 4);                         \
            if (CN) {                                                         \
                const float* pc_ = cached_prev + ro + base_ + CH + off;       \
                LD4(c##Y##0, pc_); LD4(c##Y##1, pc_ + 4);                     \
            }                                                                 \
        }                                                                     \
        WAITV(NWAIT);                                                         \
        float dd_[8] = {d##X##0[0], d##X##0[1], d##X##0[2], d##X##0[3],       \
                        d##X##1[0], d##X##1[1], d##X##1[2], d##X##1[3]};      \
        float ss_[8] = {s##X##0[0], s##X##0[1], s##X##0[2], s##X##0[3],       \
                        s##X##1[0], s##X##1[1], s##X##1[2], s##X##1[3]};      \
        float cp_[8] = {0,0,0,0,0,0,0,0};                                     \
        if (CC) {                                                             \
            cp_[0] = c##X##0[0]; cp_[1] = c##X##0[1];                         \
            cp_[2] = c##X##0[2]; cp_[3] = c##X##0[3];                         \
            cp_[4] = c##X##1[0]; cp_[5] = c##X##1[1];                         \
            cp_[6] = c##X##1[2]; cp_[7] = c##X##1[3];                         \
        }                                                                     \
        const int kb_ = base_ + off - P;                                      \
        float dp_[8], Am_[8];                                                 \
        _Pragma("unroll")                                                     \
        for (int j = 0; j < 8; ++j) {                                         \
            bool va_ = (unsigned)(kb_ + j) < span;                            \
            dp_[j] = va_ ? dd_[j] : 1.0f;                                     \
            Am_[j] = (va_ && (ss_[j] <= 0.5f)) ? 0.0f : -1.0f;                \
        }                                                                     \
        const int lo_ = (max(0, P - base_)) >> 3;                             \
        const int hi_ = (min(CH, max(0, L - base_)) + 7) >> 3;                \
        float cin_ = 0.f;                                                     \
        for (int i = lo_; i < hi_; ++i) {                                     \
            cin_ = (l == i) ? carry : cin_;                                   \
            float cc_ = carry;                                                \
            _Pragma("unroll")                                                 \
            for (int j = 0; j < 8; ++j) {                                     \
                float s_ = dp_[j] + cc_;                                      \
                cc_ = FMED3(FRACTF(s_), s_ + Am_[j], Am_[j]);                 \
            }                                                                 \
            carry = __int_as_float(                                           \
                __builtin_amdgcn_readlane(__float_as_int(cc_), i));           \
        }                                                                     \
        float pj_[8], mt_[8];                                                 \
        float c2_ = cin_;                                                     \
        _Pragma("unroll")                                                     \
        for (int j = 0; j < 8; ++j) {                                         \
            float s_  = dp_[j] + c2_;                                         \
            float t1_ = fmaxf(s_, 0.f);                                       \
            float cc_ = FMED3(FRACTF(s_), s_ + Am_[j], Am_[j]);               \
            float fv_ = t1_ - cc_;                                            \
            c2_ = cc_;                                                        \
            int u_ = base_ + off + j;                                         \
            bool va_ = (unsigned)(u_ - P) < span;                             \
            float p_ = va_ ? fv_ : ((CC && u_ < P) ? cp_[j] : 0.f);           \
            pj_[j] = p_;                                                      \
            mt_[j] = (u_ < L) ? p_ : 0.f;                                     \
        }                                                                     \
        {                                                                     \
            f32x4 m0_ = {mt_[0], mt_[1], mt_[2], mt_[3]};                     \
            f32x4 m1_ = {mt_[4], mt_[5], mt_[6], mt_[7]};                     \
            f32x4 p0_ = {pj_[0], pj_[1], pj_[2], pj_[3]};                     \
            f32x4 p1_ = {pj_[4], pj_[5], pj_[6], pj_[7]};                     \
            float* pm_ = mat  + ro + base_ + off;                             \
            float* pp_ = proj + ro + base_ + off;                             \
            float* pc2_ = cach + ro + base_ + off;                            \
            ST4(pm_, m0_);  ST4(pm_ + 4, m1_);                                \
            ST4(pp_, p0_);  ST4(pp_ + 4, p1_);                                \
            ST4(pc2_, m0_); ST4(pc2_ + 4, m1_);                               \
        }                                                                     \
    } while (0)

    // waits: k=0 -> 6 (pre1=6 newest), k=1..6 -> 10 (stores 6 + next pre 4),
    // k=7 -> 6 (stores 6 only). In-order retirement makes these exact.
    PHASE(0, A, B, 1, 1, 1, 6);
    PHASE(1, B, A, 1, 0, 1, 10);
    PHASE(2, A, B, 1, 0, 0, 10);
    PHASE(3, B, A, 1, 0, 0, 10);
    PHASE(4, A, B, 1, 0, 0, 10);
    PHASE(5, B, A, 1, 0, 0, 10);
    PHASE(6, A, B, 1, 0, 0, 10);
    PHASE(7, B, A, 0, 0, 0, 6);

    if (l == 0) {
        resid[r] = carry;
        comm[r]  = (float)L;
    }
}

extern "C" void kernel_launch(void* const* d_in, const int* in_sizes, int n_in,
                              void* d_out, int out_size, void* d_ws, size_t ws_size,
                              hipStream_t stream) {
    const float* dur            = (const float*)d_in[0];
    const float* speech         = (const float*)d_in[1];
    const float* residual_prev  = (const float*)d_in[2];
    const float* cached_prev    = (const float*)d_in[3];
    const int*   unit_len       = (const int*)d_in[4];
    const int*   sealed_len     = (const int*)d_in[5];
    const int*   committed_prev = (const int*)d_in[6];

    row_kernel<<<BB, 64, 0, stream>>>(dur, speech, residual_prev, cached_prev,
                                      unit_len, sealed_len, committed_prev,
                                      (float*)d_out);
}